// Round 2
// baseline (2126.220 us; speedup 1.0000x reference)
//
#include <hip/hip_runtime.h>

#define VOCAB 28996
#define BB 32
#define SS 512
#define DD 768
#define NCLS 9
#define ROWS (BB*SS)     // 16384
#define IN2 (2*DD)       // 1536
#define G4 (4*DD)        // 3072
#define NB2 (2*G4)       // 6144

typedef __attribute__((ext_vector_type(8))) short short8;
typedef __attribute__((ext_vector_type(4))) float floatx4;

__device__ __forceinline__ float bf2f(unsigned short u){
  union { unsigned int i; float f; } v; v.i = ((unsigned int)u) << 16; return v.f;
}
__device__ __forceinline__ unsigned short f2bf(float f){
  union { float f; unsigned int i; } v; v.f = f;
  unsigned int r = v.i + 0x7FFFu + ((v.i >> 16) & 1u);
  return (unsigned short)(r >> 16);
}
__device__ __forceinline__ float sigf(float x){ return 1.0f / (1.0f + __expf(-x)); }

__device__ __forceinline__ void gl_lds16(const unsigned short* g, unsigned short* l){
  __builtin_amdgcn_global_load_lds((__attribute__((address_space(1))) void*)(g),
                                   (__attribute__((address_space(3))) void*)(l), 16, 0, 0);
}

// ---------------- segment mean ----------------
__global__ void seg_scatter(const int* __restrict__ ids, const float* __restrict__ hidden,
                            float* __restrict__ sums, float* __restrict__ counts)
{
  int r = blockIdx.x;
  int id = ids[r];
  const float* h = hidden + (long)r * DD;
  float* s = sums + (long)id * DD;
  for (int d = threadIdx.x; d < DD; d += 256)
    atomicAdd(&s[d], h[d]);
  if (threadIdx.x == 0) atomicAdd(&counts[id], 1.0f);
}

__global__ void build_x(const int* __restrict__ ids, const float* __restrict__ hidden,
                        const float* __restrict__ sums, const float* __restrict__ counts,
                        unsigned short* __restrict__ x)
{
  int r = blockIdx.x;
  int id = ids[r];
  float inv = 1.0f / fmaxf(counts[id], 1.0f);
  const float* h = hidden + (long)r * DD;
  const float* s = sums + (long)id * DD;
  unsigned short* xr = x + (long)r * IN2;
  for (int d = threadIdx.x; d < DD; d += 256) {
    xr[d]      = f2bf(h[d]);
    xr[DD + d] = f2bf(s[d] * inv);
  }
}

// ---------------- weight conversion ----------------
__global__ void conv_bf16(const float* __restrict__ a, unsigned short* __restrict__ o, long n)
{
  long i = (long)blockIdx.x * 256 + threadIdx.x;
  if (i < n) o[i] = f2bf(a[i]);
}

__global__ void conv_bias(const float* __restrict__ bif, const float* __restrict__ bhf,
                          const float* __restrict__ bib, const float* __restrict__ bhb,
                          float* __restrict__ outb)
{
  int n = blockIdx.x * 256 + threadIdx.x;
  if (n >= NB2) return;
  outb[n] = (n < G4) ? (bif[n] + bhf[n]) : (bib[n - G4] + bhb[n - G4]);
}

// ---------------- GEMM: C[m,n] = sum_k A[m,k]*B[n,k] (+bias | +addm), bf16 in ----------------
// MODE 0: C fp32, epilogue adds bf16 addm matrix (per-z offset)
// MODE 1: C bf16, epilogue adds fp32 per-column bias
template<int MODE>
__global__ __launch_bounds__(256, 2)
void gemm_bt(const unsigned short* __restrict__ A, int lda, long sAz,
             const unsigned short* __restrict__ B, int ldb, long sBz,
             void* __restrict__ Cv, int ldc, long sCz,
             const float* __restrict__ bias,
             const unsigned short* __restrict__ addm, int ldadd, long sAddz,
             int K)
{
  __shared__ unsigned short lA[128 * 32];
  __shared__ unsigned short lB[128 * 32];
  const int z = blockIdx.z;
  A += (long)z * sAz;
  B += (long)z * sBz;

  const int t = threadIdx.x;
  const int lane = t & 63;
  const int wv = t >> 6;
  const int wm = wv >> 1, wn = wv & 1;
  const int l15 = lane & 15, q = lane >> 4;
  const long m0 = (long)blockIdx.y * 128;
  const long n0 = (long)blockIdx.x * 128;

  const int rowS = t >> 2;          // 0..63
  const int kc = (t & 3) * 8;       // 0,8,16,24
  const unsigned short* gA = A + (m0 + rowS) * lda + kc;
  const unsigned short* gB = B + (n0 + rowS) * ldb + kc;
  unsigned short* dA0 = lA + (wv << 9);           // wave-uniform LDS dest
  unsigned short* dA1 = lA + 2048 + (wv << 9);
  unsigned short* dB0 = lB + (wv << 9);
  unsigned short* dB1 = lB + 2048 + (wv << 9);

  floatx4 acc[4][4];
  #pragma unroll
  for (int i = 0; i < 4; i++)
    #pragma unroll
    for (int j = 0; j < 4; j++)
      acc[i][j] = (floatx4){0.f, 0.f, 0.f, 0.f};

  const long a64 = (long)64 * lda;
  const long b64 = (long)64 * ldb;
  for (int kt = 0; kt < K; kt += 32) {
    gl_lds16(gA + kt,       dA0);
    gl_lds16(gA + a64 + kt, dA1);
    gl_lds16(gB + kt,       dB0);
    gl_lds16(gB + b64 + kt, dB1);
    __syncthreads();
    short8 af[4], bfr[4];
    #pragma unroll
    for (int i = 0; i < 4; i++)
      af[i] = *(const short8*)(lA + (wm * 64 + i * 16 + l15) * 32 + q * 8);
    #pragma unroll
    for (int j = 0; j < 4; j++)
      bfr[j] = *(const short8*)(lB + (wn * 64 + j * 16 + l15) * 32 + q * 8);
    #pragma unroll
    for (int i = 0; i < 4; i++)
      #pragma unroll
      for (int j = 0; j < 4; j++)
        acc[i][j] = __builtin_amdgcn_mfma_f32_16x16x32_bf16(af[i], bfr[j], acc[i][j], 0, 0, 0);
    __syncthreads();
  }

  if (MODE == 0) {
    float* C = (float*)Cv + (long)z * sCz;
    const unsigned short* adm = addm + (long)z * sAddz;
    #pragma unroll
    for (int i = 0; i < 4; i++) {
      #pragma unroll
      for (int j = 0; j < 4; j++) {
        const long mg = m0 + wm * 64 + i * 16 + q * 4;
        const long ng = n0 + wn * 64 + j * 16 + l15;
        #pragma unroll
        for (int r = 0; r < 4; r++)
          C[(mg + r) * ldc + ng] = acc[i][j][r] + bf2f(adm[(mg + r) * (long)ldadd + ng]);
      }
    }
  } else {
    unsigned short* C = (unsigned short*)Cv;
    #pragma unroll
    for (int i = 0; i < 4; i++) {
      #pragma unroll
      for (int j = 0; j < 4; j++) {
        const long mg = m0 + wm * 64 + i * 16 + q * 4;
        const long ng = n0 + wn * 64 + j * 16 + l15;
        const float bb = bias[ng];
        #pragma unroll
        for (int r = 0; r < 4; r++)
          C[(mg + r) * ldc + ng] = f2bf(acc[i][j][r] + bb);
      }
    }
  }
}

// ---------------- LSTM gate / state update ----------------
// grid covers ndir*SS*DD elements; local dir ld indexes g_pre/c/h, global dir (dir0+ld)
// picks output column and time index.
__global__ void gate_step(const float* __restrict__ g_pre, int tf, int tb, int dir0,
                          float* __restrict__ c_state, unsigned short* __restrict__ h_bf,
                          unsigned short* __restrict__ out_comb)
{
  int idx = blockIdx.x * 256 + threadIdx.x;
  int ld = idx / (SS * DD);
  int rem = idx - ld * (SS * DD);
  int n = rem / DD;
  int k = rem - n * DD;
  int dir = dir0 + ld;
  int t = dir ? tb : tf;
  const float* gp = g_pre + (long)ld * SS * G4 + (long)n * G4;
  float gi = gp[k];
  float gf = gp[DD + k];
  float gg = gp[2 * DD + k];
  float go = gp[3 * DD + k];
  long ci = (long)ld * SS * DD + (long)n * DD + k;
  float c = sigf(gf) * c_state[ci] + sigf(gi) * tanhf(gg);
  float h = sigf(go) * tanhf(c);
  c_state[ci] = c;
  h_bf[ci] = f2bf(h);
  out_comb[((long)t * SS + n) * IN2 + dir * DD + k] = f2bf(h);
}

// ---------------- final linear [16384,1536](bf16) x [9,1536]^T ----------------
__global__ void final_linear(const unsigned short* __restrict__ xin, const float* __restrict__ w,
                             const float* __restrict__ b, float* __restrict__ out)
{
  __shared__ float red[NCLS * 256];
  int row = blockIdx.x;
  const unsigned short* x = xin + (long)row * IN2;
  float p[NCLS];
  #pragma unroll
  for (int c = 0; c < NCLS; c++) p[c] = 0.f;
  for (int k = threadIdx.x; k < IN2; k += 256) {
    float xv = bf2f(x[k]);
    #pragma unroll
    for (int c = 0; c < NCLS; c++) p[c] += xv * w[c * IN2 + k];
  }
  #pragma unroll
  for (int c = 0; c < NCLS; c++) red[c * 256 + threadIdx.x] = p[c];
  __syncthreads();
  for (int s = 128; s > 0; s >>= 1) {
    if (threadIdx.x < s) {
      #pragma unroll
      for (int c = 0; c < NCLS; c++)
        red[c * 256 + threadIdx.x] += red[c * 256 + threadIdx.x + s];
    }
    __syncthreads();
  }
  if (threadIdx.x < NCLS)
    out[(long)row * NCLS + threadIdx.x] = red[threadIdx.x * 256] + b[threadIdx.x];
}

extern "C" void kernel_launch(void* const* d_in, const int* in_sizes, int n_in,
                              void* d_out, int out_size, void* d_ws, size_t ws_size,
                              hipStream_t stream)
{
  const int*   batch  = (const int*)d_in[0];
  const float* hidden = (const float*)d_in[1];
  const float* w_ih_f = (const float*)d_in[2];
  const float* w_hh_f = (const float*)d_in[3];
  const float* b_ih_f = (const float*)d_in[4];
  const float* b_hh_f = (const float*)d_in[5];
  const float* w_ih_b = (const float*)d_in[6];
  const float* w_hh_b = (const float*)d_in[7];
  const float* b_ih_b = (const float*)d_in[8];
  const float* b_hh_b = (const float*)d_in[9];
  const float* lin_w  = (const float*)d_in[10];
  const float* lin_b  = (const float*)d_in[11];
  float* out = (float*)d_out;

  char* ws = (char*)d_ws;
  size_t off = 0;
  auto alloc = [&](size_t bytes) -> char* {
    char* p = ws + off;
    off += (bytes + 255) & ~(size_t)255;
    return p;
  };

  const size_t SZ_XG_A = (size_t)ROWS * NB2 * 2;        // 201.3 MB
  const size_t SZ_XG_B = (size_t)ROWS * G4  * 2;        // 100.7 MB
  const size_t SZ_XBF  = (size_t)ROWS * IN2 * 2;        //  50.3 MB
  const size_t SZ_WIH2 = (size_t)NB2 * IN2 * 2;         //  18.9 MB (both dirs)
  const size_t SZ_WIH1 = (size_t)G4  * IN2 * 2;         //   9.4 MB (one dir)
  const size_t SZ_WHH2 = (size_t)2 * G4 * DD * 2;       //   9.4 MB
  const size_t SZ_BIAS = (size_t)NB2 * 4;
  const size_t SZ_SUMS = (size_t)VOCAB * DD * 4 + (size_t)VOCAB * 4;

  const size_t NEED_A = SZ_XG_A + SZ_XBF + SZ_WIH2 + SZ_WHH2 + SZ_BIAS + 4096; // ~280.0 MB
  const bool wide = ws_size >= NEED_A;

  // weight conversions + bias are common structure; pointers differ per layout.
  if (wide) {
    // ---- Layout A: both dirs together ----
    unsigned short* xg  = (unsigned short*)alloc(SZ_XG_A);
    unsigned short* xbf = (unsigned short*)alloc(SZ_XBF);     // x_bf, later out_cmb (bf16)
    char*           wrg = alloc(SZ_WIH2);                     // wih_bf, later g_pre+h+c
    unsigned short* whh = (unsigned short*)alloc(SZ_WHH2);
    float*          bias= (float*)alloc(SZ_BIAS);
    float* sums   = (float*)xg;                               // overlay (consumed pre-xg-GEMM)
    float* counts = sums + (size_t)VOCAB * DD;
    unsigned short* wih = (unsigned short*)wrg;
    float*          g_pre   = (float*)wrg;                                   // 12.6 MB
    unsigned short* h_bf    = (unsigned short*)(wrg + (size_t)2*SS*G4*4);    //  1.6 MB
    float*          c_state = (float*)(wrg + (size_t)2*SS*G4*4 + (size_t)2*SS*DD*2); // 3.1 MB

    hipMemsetAsync(sums, 0, SZ_SUMS, stream);
    seg_scatter<<<ROWS, 256, 0, stream>>>(batch, hidden, sums, counts);
    build_x<<<ROWS, 256, 0, stream>>>(batch, hidden, sums, counts, xbf);

    conv_bf16<<<(unsigned)(((long)G4*IN2 + 255)/256), 256, 0, stream>>>(w_ih_f, wih, (long)G4*IN2);
    conv_bf16<<<(unsigned)(((long)G4*IN2 + 255)/256), 256, 0, stream>>>(w_ih_b, wih + (size_t)G4*IN2, (long)G4*IN2);
    conv_bf16<<<(unsigned)(((long)G4*DD + 255)/256), 256, 0, stream>>>(w_hh_f, whh, (long)G4*DD);
    conv_bf16<<<(unsigned)(((long)G4*DD + 255)/256), 256, 0, stream>>>(w_hh_b, whh + (size_t)G4*DD, (long)G4*DD);
    conv_bias<<<(NB2 + 255)/256, 256, 0, stream>>>(b_ih_f, b_hh_f, b_ih_b, b_hh_b, bias);

    {
      dim3 grid(NB2/128, ROWS/128, 1);
      gemm_bt<1><<<grid, 256, 0, stream>>>(xbf, IN2, 0, wih, IN2, 0,
                                           (void*)xg, NB2, 0, bias, nullptr, 0, 0, IN2);
    }
    // wih + x_bf now dead; overlay regions become live
    hipMemsetAsync(h_bf, 0, (size_t)2*SS*DD*2, stream);
    hipMemsetAsync(c_state, 0, (size_t)2*SS*DD*4, stream);

    for (int s = 0; s < BB; s++) {
      int tf = s, tb = BB - 1 - s;
      const unsigned short* adm = xg + (long)tf * SS * NB2;
      long sAdd = (long)(tb - tf) * SS * NB2 + G4;
      dim3 grid(G4/128, SS/128, 2);
      gemm_bt<0><<<grid, 256, 0, stream>>>(h_bf, DD, (long)SS*DD,
                                           whh, DD, (long)G4*DD,
                                           (void*)g_pre, G4, (long)SS*G4,
                                           nullptr, adm, NB2, sAdd, DD);
      gate_step<<<(2*SS*DD)/256, 256, 0, stream>>>(g_pre, tf, tb, 0, c_state, h_bf, xbf);
    }
    final_linear<<<ROWS, 256, 0, stream>>>(xbf, lin_w, lin_b, out);
  } else {
    // ---- Layout B: direction-sequential (~220 MB) ----
    unsigned short* xgH  = (unsigned short*)alloc(SZ_XG_B);
    unsigned short* xbf  = (unsigned short*)alloc(SZ_XBF);
    unsigned short* outc = (unsigned short*)alloc(SZ_XBF);
    char*           wrg  = alloc(SZ_WIH1);                    // wihH, later g_pre+h+c
    unsigned short* whh2 = (unsigned short*)alloc(SZ_WHH2);
    float*          bias = (float*)alloc(SZ_BIAS);
    float* sums   = (float*)xgH;                              // 89.2 MB ≤ 100.7 MB
    float* counts = sums + (size_t)VOCAB * DD;
    unsigned short* wihH = (unsigned short*)wrg;
    float*          g_preH = (float*)wrg;                                  // 6.3 MB
    unsigned short* hH     = (unsigned short*)(wrg + (size_t)SS*G4*4);     // 0.8 MB
    float*          cH     = (float*)(wrg + (size_t)SS*G4*4 + (size_t)SS*DD*2); // 1.6 MB

    hipMemsetAsync(sums, 0, SZ_SUMS, stream);
    seg_scatter<<<ROWS, 256, 0, stream>>>(batch, hidden, sums, counts);
    build_x<<<ROWS, 256, 0, stream>>>(batch, hidden, sums, counts, xbf);

    conv_bf16<<<(unsigned)(((long)G4*DD + 255)/256), 256, 0, stream>>>(w_hh_f, whh2, (long)G4*DD);
    conv_bf16<<<(unsigned)(((long)G4*DD + 255)/256), 256, 0, stream>>>(w_hh_b, whh2 + (size_t)G4*DD, (long)G4*DD);
    conv_bias<<<(NB2 + 255)/256, 256, 0, stream>>>(b_ih_f, b_hh_f, b_ih_b, b_hh_b, bias);

    for (int dir = 0; dir < 2; dir++) {
      conv_bf16<<<(unsigned)(((long)G4*IN2 + 255)/256), 256, 0, stream>>>(
          dir ? w_ih_b : w_ih_f, wihH, (long)G4*IN2);
      {
        dim3 grid(G4/128, ROWS/128, 1);
        gemm_bt<1><<<grid, 256, 0, stream>>>(xbf, IN2, 0, wihH, IN2, 0,
                                             (void*)xgH, G4, 0, bias + (size_t)dir*G4,
                                             nullptr, 0, 0, IN2);
      }
      hipMemsetAsync(hH, 0, (size_t)SS*DD*2, stream);
      hipMemsetAsync(cH, 0, (size_t)SS*DD*4, stream);
      for (int s = 0; s < BB; s++) {
        int tf = s, tb = BB - 1 - s;
        int t = dir ? tb : tf;
        const unsigned short* adm = xgH + (long)t * SS * G4;
        dim3 grid(G4/128, SS/128, 1);
        gemm_bt<0><<<grid, 256, 0, stream>>>(hH, DD, 0,
                                             whh2 + (size_t)dir*G4*DD, DD, 0,
                                             (void*)g_preH, G4, 0,
                                             nullptr, adm, G4, 0, DD);
        gate_step<<<(SS*DD)/256, 256, 0, stream>>>(g_preH, tf, tb, dir, cH, hH, outc);
      }
    }
    final_linear<<<ROWS, 256, 0, stream>>>(outc, lin_w, lin_b, out);
  }
}